// Round 1
// baseline (17.787 us; speedup 1.0000x reference)
//
#include <hip/hip_runtime.h>

#define NN 10
#define CELLS 100
#define BIGV 1000000.0f

__global__ __launch_bounds__(128) void custom_loss_last_kernel(
    const float* __restrict__ result_given,
    const int*   __restrict__ points_given,
    const float* __restrict__ weightmatrix,
    const float* __restrict__ weight_weight,
    float* __restrict__ out, int B)
{
    const int t = threadIdx.x;
    const int b = B - 1;

    __shared__ float res[CELLS];
    __shared__ float wmv[CELLS];
    __shared__ int   lab[CELLS];
    __shared__ int   msk[CELLS];
    __shared__ int   changed;
    __shared__ float red_sum[128];
    __shared__ float red_rw[128];
    __shared__ float red_min[128];
    __shared__ int   red_cnt[128];

    if (t < CELLS) {
        float rv = result_given[(size_t)b * CELLS + t];
        float wv = weightmatrix[(size_t)b * CELLS + t];
        res[t] = rv;
        wmv[t] = wv;
        int m = (rintf(rv) != 0.0f) ? 1 : 0;   // round-half-to-even, matches jnp.round
        msk[t] = m;
        lab[t] = m ? (t + 1) : 0;
    }
    __syncthreads();

    const int ti = t / NN, tj = t % NN;

    // 8-connected min-label propagation (== reference's 100-iter scan; early
    // exit on convergence is exact since post-convergence iters are no-ops).
    for (int it = 0; it < 100; ++it) {
        if (t == 0) changed = 0;
        int nm = 0x7fffffff;
        if (t < CELLS && msk[t]) {
            nm = lab[t];
            #pragma unroll
            for (int di = -1; di <= 1; ++di) {
                int ni = ti + di;
                if (ni < 0 || ni >= NN) continue;
                #pragma unroll
                for (int dj = -1; dj <= 1; ++dj) {
                    int nj = tj + dj;
                    if (nj < 0 || nj >= NN) continue;
                    int nidx = ni * NN + nj;
                    if (msk[nidx]) nm = min(nm, lab[nidx]);
                }
            }
        }
        __syncthreads();  // all reads of lab done before writes
        if (t < CELLS && msk[t] && nm < lab[t]) { lab[t] = nm; changed = 1; }
        __syncthreads();  // writes (lab, changed) visible
        if (!changed) break;
    }

    const int p00 = points_given[(size_t)b * 4 + 0];
    const int p01 = points_given[(size_t)b * 4 + 1];
    const int p10 = points_given[(size_t)b * 4 + 2];
    const int p11 = points_given[(size_t)b * 4 + 3];
    const int sv = lab[p00 * NN + p01];
    const int ev = lab[p10 * NN + p11];

    // per-thread partials
    float psum = 0.0f, prw = 0.0f, pmin = BIGV;
    int   pcnt = 0;
    if (t < CELLS) {
        float rv = res[t];
        psum = rv;
        prw  = rv * wmv[t];
        bool sm = (sv > 0) && (lab[t] == sv);
        pcnt = sm ? 1 : 0;
        if (sm && ev > 0) {
            for (int j = 0; j < CELLS; ++j) {
                if (lab[j] == ev) {
                    int d = abs(ti - j / NN) + abs(tj - j % NN);
                    float fd = (float)d;
                    if (fd < pmin) pmin = fd;
                }
            }
        }
    }
    red_sum[t] = psum;
    red_rw[t]  = prw;
    red_min[t] = pmin;
    red_cnt[t] = pcnt;
    __syncthreads();

    if (t == 0) {
        float sum_res = 0.0f, sum_rw = 0.0f, mn = BIGV;
        int cnt = 0;
        for (int k = 0; k < 128; ++k) {
            sum_res += red_sum[k];
            sum_rw  += red_rw[k];
            mn       = fminf(mn, red_min[k]);
            cnt     += red_cnt[k];
        }
        const float r0 = res[p00 * NN + p01];
        const float r1 = res[p10 * NN + p11];
        const float manhattan = (float)(abs(p10 - p00) + abs(p11 - p01));
        const bool  gap_cond  = (sv > 0) && (ev > 0);
        const float soa_inv   = 100.0f - sum_res;
        const float gap_loss  = gap_cond ? mn * soa_inv * 5000.0f
                                         : (2.0f - (r0 + r1)) * 20000.0f;
        const float min_distance = gap_cond ? mn : manhattan;
        const bool  cond_start = (rintf(r0) == 0.0f) || (r1 == 0.0f);
        const float loss_start = cond_start ? (2.0f - (r0 + r1)) * 20000.0f : 0.0f;
        const float len_start  = gap_cond ? (float)cnt : 0.0f;
        const float csp = sum_rw * weight_weight[0] * fabsf(manhattan - len_start);
        out[0] = loss_start + csp + gap_loss;
        out[1] = min_distance;
    }
}

extern "C" void kernel_launch(void* const* d_in, const int* in_sizes, int n_in,
                              void* d_out, int out_size, void* d_ws, size_t ws_size,
                              hipStream_t stream) {
    const float* result_given  = (const float*)d_in[0];
    const int*   points_given  = (const int*)d_in[1];
    const float* weightmatrix  = (const float*)d_in[2];
    const float* weight_weight = (const float*)d_in[3];
    float* out = (float*)d_out;
    const int B = in_sizes[0] / CELLS;

    custom_loss_last_kernel<<<1, 128, 0, stream>>>(
        result_given, points_given, weightmatrix, weight_weight, out, B);
}

// Round 2
// 9.734 us; speedup vs baseline: 1.8272x; 1.8272x over previous
//
#include <hip/hip_runtime.h>

#define NN 10
#define CELLS 100
#define BIGV 1000000.0f

// 128-bit bitboard: bit p = cell p (row-major, p = row*10 + col).
// word lo = cells 0..63, word hi = cells 64..127 (virtual rows >= 10 allowed
// during unmasked L1 dilation; they can never shorten a path).
struct U128 { unsigned long long lo, hi; };

__device__ __forceinline__ U128 u_or (U128 a, U128 b){ return {a.lo|b.lo, a.hi|b.hi}; }
__device__ __forceinline__ U128 u_and(U128 a, U128 b){ return {a.lo&b.lo, a.hi&b.hi}; }
__device__ __forceinline__ bool u_any(U128 a){ return (a.lo|a.hi)!=0ull; }
__device__ __forceinline__ bool u_eq (U128 a, U128 b){ return a.lo==b.lo && a.hi==b.hi; }
template<int K> __device__ __forceinline__ U128 shl(U128 a){
    return { a.lo<<K, (a.hi<<K)|(a.lo>>(64-K)) };
}
template<int K> __device__ __forceinline__ U128 shr(U128 a){
    return { (a.lo>>K)|(a.hi<<(64-K)), a.hi>>K };
}
__device__ __forceinline__ bool u_bit(U128 a, int i){
    return ((i<64 ? (a.lo>>i) : (a.hi>>(i-64))) & 1ull) != 0ull;
}
__device__ __forceinline__ U128 u_onebit(int i){
    U128 r{0,0};
    if (i<64) r.lo = 1ull<<i; else r.hi = 1ull<<(i-64);
    return r;
}
__device__ __forceinline__ int u_popc(U128 a){
    return __popcll(a.lo) + __popcll(a.hi);
}

// col-0 / col-9 masks extended periodically over all 128 bits (p%10)
#define COL0_LO 0x1004010040100401ull
#define COL0_HI 0x0100401004010040ull
#define COL9_LO 0x0802008020080200ull
#define COL9_HI 0x0080200802008020ull

__device__ __forceinline__ U128 dilate8(U128 S, U128 M){
    U128 A = { S.lo & ~COL0_LO, S.hi & ~COL0_HI };  // may move left  (col-1)
    U128 B = { S.lo & ~COL9_LO, S.hi & ~COL9_HI };  // may move right (col+1)
    U128 r = S;
    r = u_or(r, shr<1 >(A)); r = u_or(r, shr<11>(A)); r = u_or(r, shl<9 >(A));
    r = u_or(r, shl<1 >(B)); r = u_or(r, shr<9 >(B)); r = u_or(r, shl<11>(B));
    r = u_or(r, shr<10>(S)); r = u_or(r, shl<10>(S));
    return u_and(r, M);
}

__device__ __forceinline__ U128 dilate4(U128 S){
    U128 A = { S.lo & ~COL0_LO, S.hi & ~COL0_HI };
    U128 B = { S.lo & ~COL9_LO, S.hi & ~COL9_HI };
    U128 r = S;
    r = u_or(r, shr<1 >(A));
    r = u_or(r, shl<1 >(B));
    r = u_or(r, shr<10>(S)); r = u_or(r, shl<10>(S));
    return r;
}

__device__ __forceinline__ U128 flood(int seed, U128 M){
    U128 S = u_onebit(seed);
    for (int i = 0; i < 100; ++i){
        U128 Sn = dilate8(S, M);
        if (u_eq(Sn, S)) break;
        S = Sn;
    }
    return S;
}

__global__ __launch_bounds__(64) void custom_loss_last_kernel(
    const float* __restrict__ result_given,
    const int*   __restrict__ points_given,
    const float* __restrict__ weightmatrix,
    const float* __restrict__ weight_weight,
    float* __restrict__ out, int B)
{
    const int t = threadIdx.x;          // 0..63, one wave
    const int b = B - 1;
    const float* rp = result_given + (size_t)b * CELLS;
    const float* wp = weightmatrix + (size_t)b * CELLS;

    // each lane owns cell t and (if t<36) cell t+64
    float rv0 = rp[t], wv0 = wp[t];
    float rv1 = 0.0f, wv1 = 0.0f;
    if (t < CELLS - 64) { rv1 = rp[64 + t]; wv1 = wp[64 + t]; }

    // wave-butterfly sums (identical result in all lanes)
    float psum = rv0 + rv1;
    float prw  = rv0 * wv0 + rv1 * wv1;
    #pragma unroll
    for (int k = 32; k >= 1; k >>= 1) {
        psum += __shfl_xor(psum, k);
        prw  += __shfl_xor(prw,  k);
    }

    // mask bitboard via ballot (round-half-even matches jnp.round)
    unsigned long long m0 = __ballot(rintf(rv0) != 0.0f);
    unsigned long long m1 = __ballot((t < CELLS - 64) && (rintf(rv1) != 0.0f));
    U128 M = { m0, m1 };

    // points (uniform scalar loads)
    const int p00 = points_given[(size_t)b*4 + 0];
    const int p01 = points_given[(size_t)b*4 + 1];
    const int p10 = points_given[(size_t)b*4 + 2];
    const int p11 = points_given[(size_t)b*4 + 3];
    const int i0 = p00 * NN + p01;
    const int i1 = p10 * NN + p11;

    // r0, r1 via shuffle from owning lane
    float sel0 = (i0 < 64) ? rv0 : rv1;
    float r0 = __shfl(sel0, i0 & 63);
    float sel1 = (i1 < 64) ? rv0 : rv1;
    float r1 = __shfl(sel1, i1 & 63);

    const bool sv = u_bit(M, i0);       // start cell in mask <=> sv>0
    const bool ev = u_bit(M, i1);
    const bool gap_cond = sv && ev;

    float mnf = BIGV;
    int   lenstart = 0;
    if (gap_cond) {
        U128 S = flood(i0, M);          // start component
        U128 E = flood(i1, M);          // end component
        lenstart = u_popc(S);
        // min L1 distance between sets = diamond-dilation count until overlap
        int d = 0;
        U128 T = S;
        while (!u_any(u_and(T, E)) && d < 32) { T = dilate4(T); ++d; }
        mnf = (float)d;
    }

    const float manhattan = (float)(abs(p10 - p00) + abs(p11 - p01));
    const float soa_inv   = 100.0f - psum;
    const float gap_loss  = gap_cond ? mnf * soa_inv * 5000.0f
                                     : (2.0f - (r0 + r1)) * 20000.0f;
    const float min_distance = gap_cond ? mnf : manhattan;
    const bool  cond_start = (rintf(r0) == 0.0f) || (r1 == 0.0f);
    const float loss_start = cond_start ? (2.0f - (r0 + r1)) * 20000.0f : 0.0f;
    const float len_start  = gap_cond ? (float)lenstart : 0.0f;
    const float csp = prw * weight_weight[0] * fabsf(manhattan - len_start);

    if (t == 0) {
        out[0] = loss_start + csp + gap_loss;
        out[1] = min_distance;
    }
}

extern "C" void kernel_launch(void* const* d_in, const int* in_sizes, int n_in,
                              void* d_out, int out_size, void* d_ws, size_t ws_size,
                              hipStream_t stream) {
    const float* result_given  = (const float*)d_in[0];
    const int*   points_given  = (const int*)d_in[1];
    const float* weightmatrix  = (const float*)d_in[2];
    const float* weight_weight = (const float*)d_in[3];
    float* out = (float*)d_out;
    const int B = in_sizes[0] / CELLS;

    custom_loss_last_kernel<<<1, 64, 0, stream>>>(
        result_given, points_given, weightmatrix, weight_weight, out, B);
}